// Round 5
// baseline (452.941 us; speedup 1.0000x reference)
//
#include <hip/hip_runtime.h>
#include <hip/hip_bf16.h>

typedef short s16x8 __attribute__((ext_vector_type(8)));      // 8 bf16 (4 VGPRs)
typedef float f32x16 __attribute__((ext_vector_type(16)));
typedef unsigned short us8 __attribute__((ext_vector_type(8)));

#define HE   1024
#define SEQ  4096
#define NBAT 32
#define BM   64      // rows per block
#define BKG  64      // k per group (one barrier per group)
#define NG   16      // HE / BKG

__device__ __forceinline__ unsigned short f2bf(float f) {
    unsigned u = __builtin_bit_cast(unsigned, f);
    u += 0x7FFFu + ((u >> 16) & 1u);
    return (unsigned short)(u >> 16);
}

__device__ __forceinline__ float tanh_fast(float x) {
    float e = __expf(2.0f * x);
    return 1.0f - 2.0f / (e + 1.0f);
}

// barrier WITHOUT vmcnt drain: only LDS ops must be cross-wave visible;
// register-destined global loads stay in flight across it.
#define WG_SYNC() do {                                         \
    asm volatile("s_waitcnt lgkmcnt(0)" ::: "memory");         \
    __builtin_amdgcn_s_barrier();                              \
} while (0)

// ---- h_proj partials
__global__ void k_hproj(const float* __restrict__ hidden, const float* __restrict__ W,
                        float* __restrict__ cpart) {
    int b = blockIdx.x >> 3, kc = blockIdx.x & 7;
    int h = threadIdx.x;
    const float* hv = hidden + (NBAT + b) * HE;   // hidden[-1]
    int k0 = kc * 128;
    float acc = 0.f;
    for (int j = 0; j < 128; ++j)
        acc = fmaf(hv[k0 + j], W[(k0 + j) * HE + h], acc);
    cpart[(b * 8 + kc) * HE + h] = acc;
}

__global__ void k_cfinal(const float* __restrict__ cpart, const float* __restrict__ b_attn,
                         float* __restrict__ c) {
    int b = blockIdx.x, h = threadIdx.x;
    float s = b_attn[h];
    #pragma unroll
    for (int kc = 0; kc < 8; ++kc) s += cpart[(b * 8 + kc) * HE + h];
    c[b * HE + h] = s;
}

// ---- pack W_e (= W_attn[He:]) into 32x32x16 MFMA B-fragment order:
// Wp[((kb2*32 + cf)*64 + l)*8 + i] = bf16( W_e[kb2*16 + (l>>5)*8 + i][cf*32 + (l&31)] )
__global__ void k_pack(const float* __restrict__ W, unsigned short* __restrict__ Wp) {
    int gid = blockIdx.x * blockDim.x + threadIdx.x;   // 131072 threads
    int l = gid & 63, cf = (gid >> 6) & 31, kb2 = gid >> 11;
    int krow = HE + kb2 * 16 + ((l >> 5) * 8);
    int col  = cf * 32 + (l & 31);
    us8 v;
    #pragma unroll
    for (int i = 0; i < 8; ++i) v[i] = f2bf(W[(krow + i) * HE + col]);
    *(us8*)(Wp + (long)gid * 8) = v;
}

// ---- main fused kernel: 64 rows x 1024 cols per block, 512 threads (8 waves),
//      half-group-deep register B prefetch => NO vmcnt waits inside MFMA phases
__global__ __launch_bounds__(512, 2) void k_main(
    const float* __restrict__ E, const us8* __restrict__ Wp,
    const float* __restrict__ C, const float* __restrict__ VW,
    float* __restrict__ scores)
{
    __shared__ unsigned short Abuf[2][BM * BKG];   // 2 x 8 KB, swizzled bf16 E tile
    __shared__ float smred[BM][8];

    const int tid  = threadIdx.x;
    const int lane = tid & 63;
    const int wv   = tid >> 6;           // wave 0..7, col-frags wv*4..+3
    const int m0   = blockIdx.x * BM;
    const int bb   = m0 >> 12;

    // E staging: 512 threads x 8 floats = 64 rows x 64 k per group
    const int s_row = tid >> 3;
    const int s_kq  = tid & 7;           // 8-float (=16B bf16) chunk within row
    const float* gE = E + (long)(m0 + s_row) * HE + s_kq * 8;
    char* const a_wr0 = (char*)&Abuf[0][0] + s_row * 128 + ((s_kq ^ (s_row & 7)) << 4);
    char* const a_wr1 = (char*)&Abuf[1][0] + s_row * 128 + ((s_kq ^ (s_row & 7)) << 4);

    // A-frag read map: row = rf*32 + (lane&31), k = stp*16 + (lane>>5)*8 + i
    const int l31 = lane & 31, lh = lane >> 5;
    const int a_sw = l31 & 7;            // row&7 (same for rf=0,1)
    const int a_r0 = l31 * 128;
    const int a_r1 = (32 + l31) * 128;

    // B: chunk id = kb2*32 + wv*4 + cfi, 1 KB each, lane offset 16B
    const char* WpB = (const char*)Wp + ((long)(wv * 4) << 10) + lane * 16;

    f32x16 acc[2][4];
    #pragma unroll
    for (int rf = 0; rf < 2; ++rf)
        #pragma unroll
        for (int cfi = 0; cfi < 4; ++cfi)
            #pragma unroll
            for (int e = 0; e < 16; ++e) acc[rf][cfi][e] = 0.f;

#define LOADB_SET(set, kb2base)                                                  \
    _Pragma("unroll")                                                            \
    for (int s_ = 0; s_ < 2; ++s_)                                               \
        _Pragma("unroll")                                                        \
        for (int cfi = 0; cfi < 4; ++cfi)                                        \
            set[s_ * 4 + cfi] = *(const s16x8*)(WpB +                            \
                (((long)((kb2base) + s_) * 32 + cfi) << 10));

#define AREAD2(d0, d1, Ab, stp) do {                                             \
    const int o_ = ((((stp) * 2 + lh) ^ a_sw) << 4);                             \
    d0 = *(const s16x8*)((Ab) + a_r0 + o_);                                      \
    d1 = *(const s16x8*)((Ab) + a_r1 + o_);                                      \
} while (0)

#define MFMA_STEP(a0_, a1_, bset, si) do {                                       \
    __builtin_amdgcn_s_setprio(1);                                               \
    _Pragma("unroll")                                                            \
    for (int cfi = 0; cfi < 4; ++cfi)                                            \
        acc[0][cfi] = __builtin_amdgcn_mfma_f32_32x32x16_bf16(                   \
            a0_, bset[(si) * 4 + cfi], acc[0][cfi], 0, 0, 0);                    \
    _Pragma("unroll")                                                            \
    for (int cfi = 0; cfi < 4; ++cfi)                                            \
        acc[1][cfi] = __builtin_amdgcn_mfma_f32_32x32x16_bf16(                   \
            a1_, bset[(si) * 4 + cfi], acc[1][cfi], 0, 0, 0);                    \
    __builtin_amdgcn_s_setprio(0);                                               \
} while (0)

#define STAGE_WRITE(ptr) do {                                                    \
    us8 w_;                                                                      \
    w_[0]=f2bf(evA.x); w_[1]=f2bf(evA.y); w_[2]=f2bf(evA.z); w_[3]=f2bf(evA.w);  \
    w_[4]=f2bf(evB.x); w_[5]=f2bf(evB.y); w_[6]=f2bf(evB.z); w_[7]=f2bf(evB.w);  \
    *(us8*)(ptr) = w_;                                                           \
} while (0)

    s16x8 bU[8], bV[8];
    s16x8 x0, x1, y0, y1;
    float4 evA, evB;

    // prologue: E(0) staged to buf0; B steps {0,1} -> bU
    evA = *(const float4*)(gE);
    evB = *(const float4*)(gE + 4);
    LOADB_SET(bU, 0);
    STAGE_WRITE(a_wr0);          // implicit vmcnt wait for evA/evB (prologue only)
    WG_SYNC();

    for (int g = 0; g < NG; ++g) {
        const char* Ab = (const char*)&Abuf[g & 1][0];
        const int kb2 = g * 4;

        // issue order matters: [V(half1), E(g+1)] ... [U(g+1 half0)]
        LOADB_SET(bV, kb2 + 2);
        if (g + 1 < NG) {
            evA = *(const float4*)(gE + (g + 1) * BKG);
            evB = *(const float4*)(gE + (g + 1) * BKG + 4);
        }

        // phase A: steps 0,1 with bU (loaded a half-group ago)
        AREAD2(x0, x1, Ab, 0);
        AREAD2(y0, y1, Ab, 1);
        MFMA_STEP(x0, x1, bU, 0);
        MFMA_STEP(y0, y1, bU, 1);

        // phase B: steps 2,3 with bV; prefetch U for next group
        {
            const int nb = (g + 1 < NG) ? (kb2 + 4) : kb2;   // clamp (data unused at tail)
            LOADB_SET(bU, nb);
        }
        AREAD2(x0, x1, Ab, 2);
        AREAD2(y0, y1, Ab, 3);
        MFMA_STEP(x0, x1, bV, 0);
        MFMA_STEP(y0, y1, bV, 1);

        if (g + 1 < NG) {
            char* awr = (g & 1) ? a_wr0 : a_wr1;   // write buf (g+1)&1
            STAGE_WRITE(awr);                      // implicit vmcnt(8): waits E only
        }
        WG_SYNC();
    }

#undef LOADB_SET
#undef AREAD2
#undef MFMA_STEP
#undef STAGE_WRITE

    // fused epilogue: score[row] = sum_col v_w[col] * tanh(acc + c[b][col])
    float cv[4], vv[4];
    #pragma unroll
    for (int cfi = 0; cfi < 4; ++cfi) {
        int col = (wv * 4 + cfi) * 32 + l31;
        cv[cfi] = C[bb * HE + col];
        vv[cfi] = VW[col];
    }
    #pragma unroll
    for (int rf = 0; rf < 2; ++rf) {
        #pragma unroll
        for (int reg = 0; reg < 16; ++reg) {
            float pS = 0.f;
            #pragma unroll
            for (int cfi = 0; cfi < 4; ++cfi)
                pS += tanh_fast(acc[rf][cfi][reg] + cv[cfi]) * vv[cfi];
            pS += __shfl_xor(pS, 1);
            pS += __shfl_xor(pS, 2);
            pS += __shfl_xor(pS, 4);
            pS += __shfl_xor(pS, 8);
            pS += __shfl_xor(pS, 16);
            if (l31 == 0) {
                int row = rf * 32 + (reg & 3) + 8 * (reg >> 2) + 4 * lh;
                smred[row][wv] = pS;
            }
        }
    }
    __syncthreads();
    if (tid < BM) {
        float s = 0.f;
        #pragma unroll
        for (int ww = 0; ww < 8; ++ww) s += smred[tid][ww];
        scores[m0 + tid] = s;
    }
}

// ---- softmax over S=4096 per batch row
__global__ void k_softmax(const float* __restrict__ scores, float* __restrict__ out) {
    __shared__ float red[16];
    __shared__ float red2[16];
    int b = blockIdx.x, tid = threadIdx.x;
    const float* s = scores + b * SEQ;
    float v[4];
    float mx = -1e30f;
    #pragma unroll
    for (int j = 0; j < 4; ++j) { v[j] = s[tid + j * 1024]; mx = fmaxf(mx, v[j]); }
    #pragma unroll
    for (int off = 32; off; off >>= 1) mx = fmaxf(mx, __shfl_xor(mx, off));
    if ((tid & 63) == 0) red[tid >> 6] = mx;
    __syncthreads();
    mx = red[0];
    #pragma unroll
    for (int i = 1; i < 16; ++i) mx = fmaxf(mx, red[i]);
    float sum = 0.f;
    #pragma unroll
    for (int j = 0; j < 4; ++j) { v[j] = expf(v[j] - mx); sum += v[j]; }
    #pragma unroll
    for (int off = 32; off; off >>= 1) sum += __shfl_xor(sum, off);
    if ((tid & 63) == 0) red2[tid >> 6] = sum;
    __syncthreads();
    sum = 0.f;
    #pragma unroll
    for (int i = 0; i < 16; ++i) sum += red2[i];
    float inv = 1.0f / sum;
    #pragma unroll
    for (int j = 0; j < 4; ++j) out[b * SEQ + tid + j * 1024] = v[j] * inv;
}

extern "C" void kernel_launch(void* const* d_in, const int* in_sizes, int n_in,
                              void* d_out, int out_size, void* d_ws, size_t ws_size,
                              hipStream_t stream)
{
    const float* hidden = (const float*)d_in[0];
    const float* enc    = (const float*)d_in[1];
    const float* W      = (const float*)d_in[2];
    const float* b_attn = (const float*)d_in[3];
    const float* v_w    = (const float*)d_in[4];
    float* out          = (float*)d_out;

    char* ws = (char*)d_ws;
    unsigned short* Wp = (unsigned short*)(ws);                        // 2 MB packed bf16 W_e
    float* cpart       = (float*)(ws + (2u << 20));                    // 1 MB
    float* Cc          = (float*)(ws + (3u << 20));                    // 128 KB
    float* scores      = (float*)(ws + (3u << 20) + (128u << 10));     // 512 KB

    k_pack   <<<512, 256,  0, stream>>>(W, Wp);
    k_hproj  <<<256, 1024, 0, stream>>>(hidden, W, cpart);
    k_cfinal <<<32,  1024, 0, stream>>>(cpart, b_attn, Cc);
    k_main   <<<2048, 512, 0, stream>>>(enc, (const us8*)Wp, Cc, v_w, scores);
    k_softmax<<<32,  1024, 0, stream>>>(scores, out);
}